// Round 1
// 54.756 us; speedup vs baseline: 1.2462x; 1.2462x over previous
//
#include <hip/hip_runtime.h>
#include <hip/hip_bf16.h>

#define NPIX 65536
#define H_EPS 1e-6f
#define SIG2 4e-4f    // sigma^2; weights are 1/(d^2+sigma^2) — uniform
                      // sigma^-4 scale cancels in the final normalization

typedef __bf16 bf16x8 __attribute__((ext_vector_type(8)));
typedef float  f32x4  __attribute__((ext_vector_type(4)));

// hist[l,c,u,v] = sum_n du[l,n,c,u] * dv[l,n,c,v]
// Grid (npart, 12): block = 4 waves. Per 1024-pixel round: one vectorized
// staging pass + ONE barrier, then each wave independently computes 8 K=32
// chunks into its private 64x64 accumulator (4x4 fragments of
// mfma_f32_16x16x32_bf16). The chunk loop is deliberately NOT unrolled:
// unrolled, the body is ~3k instructions (~24 KB) and thrashes the I-cache
// (R4: all pipes idle at 51 us). Rolled body ~300 instr stays resident.
// Epilogue (R5): cross-wave LDS reduction (32 KB redv, 2 halves) so each
// BLOCK stores one 16 KB fragment-linear partial instead of 4 per-wave
// ones — partial traffic 50.3 -> 12.6 MB on both the store and the
// reduce_partials read side. LDS 44 KB/block keeps 3 blocks/CU.
// reduce_partials unscrambles fragment order to (u,v) on its tiny write side.
// No atomics anywhere.
__global__ __launch_bounds__(256, 3)
void hist_kernel(const float* __restrict__ x, float* __restrict__ partial,
                 int npart)
{
    const int part = blockIdx.x;
    const int lc   = blockIdx.y;      // 0..11
    const int l    = lc / 3;
    const int c    = lc % 3;
    const int tid  = threadIdx.x;
    const int wave = tid >> 6;
    const int lane = tid & 63;
    const int g    = lane >> 4;       // 16-lane group
    const int m    = lane & 15;       // row (A) / col (B) index

    __shared__ float stage[3][1024];  // Iu, Iv, Iy for 1024 pixels
                                      // (group read stride 8 dwords -> banks
                                      // {0,8,16,24}: conflict-free, measured)
    __shared__ f32x4 redv[4][8][64];  // 32 KB cross-wave reduction buffer

    float lin_t[4];
#pragma unroll
    for (int t = 0; t < 4; ++t)
        lin_t[t] = -3.0f + (float)(t * 16 + m) * (6.0f / 63.0f);

    f32x4 acc[4][4];
#pragma unroll
    for (int a = 0; a < 4; ++a)
#pragma unroll
        for (int b = 0; b < 4; ++b)
            acc[a][b] = (f32x4){0.f, 0.f, 0.f, 0.f};

    const float* xl = x + (size_t)l * 3u * NPIX;
    const int px_per_block = NPIX / npart;
    const int rounds = px_per_block >> 10;          // 1024-px rounds
    const int base = part * px_per_block;

    for (int rd = 0; rd < rounds; ++rd) {
        if (rd) __syncthreads();      // protect stage overwrite
        // ---- stage 1024 pixels: Iu_c, Iv_c, Iy (4 px/thread, vectorized) ----
        {
            const int p0 = base + (rd << 10) + (tid << 2);
            f32x4 r0 = *(const f32x4*)&xl[p0];
            f32x4 r1 = *(const f32x4*)&xl[p0 + NPIX];
            f32x4 r2 = *(const f32x4*)&xl[p0 + 2 * NPIX];
            f32x4 ou, ov, oy;
#pragma unroll
            for (int k = 0; k < 4; ++k) {
                float v0 = fminf(fmaxf(fmaf(r0[k], 0.5f, 0.5f), 0.f), 1.f);
                float v1 = fminf(fmaxf(fmaf(r1[k], 0.5f, 0.5f), 0.f), 1.f);
                float v2 = fminf(fmaxf(fmaf(r2[k], 0.5f, 0.5f), 0.f), 1.f);
                oy[k] = sqrtf(fmaf(v0, v0, fmaf(v1, v1, fmaf(v2, v2, H_EPS))));
                float l0 = __logf(v0 + H_EPS);
                float l1 = __logf(v1 + H_EPS);
                float l2 = __logf(v2 + H_EPS);
                // Iu = logI - logI[..., [1,0,0]] ; Iv = logI - logI[..., [2,2,1]]
                float lcur = (c == 0) ? l0 : ((c == 1) ? l1 : l2);
                float lu   = (c == 0) ? l1 : l0;
                float lv   = (c == 2) ? l1 : l2;
                ou[k] = lcur - lu;
                ov[k] = lcur - lv;
            }
            *(f32x4*)&stage[0][tid << 2] = ou;
            *(f32x4*)&stage[1][tid << 2] = ov;
            *(f32x4*)&stage[2][tid << 2] = oy;
        }
        __syncthreads();

        // ---- each wave: 8 independent K=32 chunks, no further sync ----
        // NOT unrolled (I-cache); all inner indexing stays compile-time.
#pragma unroll 1
        for (int chunk = 0; chunk < 8; ++chunk) {
            const int pb = wave * 256 + chunk * 32 + g * 8;
            float iu[8], iv[8], iy[8];
#pragma unroll
            for (int j = 0; j < 8; ++j) {       // 16-lane broadcast reads
                iu[j] = stage[0][pb + j];
                iv[j] = stage[1][pb + j];
                iy[j] = stage[2][pb + j];
            }
            bf16x8 afrag[4], bfrag[4];
#pragma unroll
            for (int j = 0; j < 8; ++j) {
#pragma unroll
                for (int t = 0; t < 4; ++t) {
                    float da = iu[j] - lin_t[t];
                    afrag[t][j] = (__bf16)(iy[j] *
                        __builtin_amdgcn_rcpf(fmaf(da, da, SIG2)));
                    float db = iv[j] - lin_t[t];
                    bfrag[t][j] = (__bf16)
                        __builtin_amdgcn_rcpf(fmaf(db, db, SIG2));
                }
            }
#pragma unroll
            for (int mt = 0; mt < 4; ++mt)
#pragma unroll
                for (int nt = 0; nt < 4; ++nt)
                    acc[mt][nt] = __builtin_amdgcn_mfma_f32_16x16x32_bf16(
                        afrag[mt], bfrag[nt], acc[mt][nt], 0, 0, 0);
        }
    }

    // ---- cross-wave LDS reduction: ONE 16 KB partial per block ----
    // Two halves of 8 fragments each; fragment-linear order preserved so
    // reduce_partials' unscramble is unchanged (frag index = h*8 + f).
    f32x4* dstv = (f32x4*)(partial + (size_t)(lc * npart + part) * 4096);
#pragma unroll
    for (int h = 0; h < 2; ++h) {
        if (h) __syncthreads();       // half-0 reads done before overwrite
#pragma unroll
        for (int f = 0; f < 8; ++f) {
            const int frag = h * 8 + f;
            redv[wave][f][lane] = acc[frag >> 2][frag & 3];
        }
        __syncthreads();
#pragma unroll
        for (int q = 0; q < 2; ++q) {
            const int idx = q * 256 + tid;   // frag-linear within this half
            f32x4 s = redv[0][idx >> 6][idx & 63];
            s += redv[1][idx >> 6][idx & 63];
            s += redv[2][idx >> 6][idx & 63];
            s += redv[3][idx >> 6][idx & 63];
            dstv[h * 512 + idx] = s;         // fully coalesced dwordx4
        }
    }
}

// hist[lc][u][v] = sum_s partial[lc][s][frag(u,v)]; reads fully coalesced in
// fragment order, the (u,v) unscramble happens on the tiny write side.
__global__ __launch_bounds__(256)
void reduce_partials(const float* __restrict__ partial, float* __restrict__ hist,
                     int nslice)
{
    const int lc = blockIdx.y;
    const int i  = (blockIdx.x << 8) | threadIdx.x;   // fragment-linear index
    const float* p = partial + (size_t)lc * nslice * 4096 + i;
    float s0 = 0.f, s1 = 0.f, s2 = 0.f, s3 = 0.f;
    int k = 0;
    for (; k + 4 <= nslice; k += 4) {
        s0 += p[(size_t)(k + 0) * 4096];
        s1 += p[(size_t)(k + 1) * 4096];
        s2 += p[(size_t)(k + 2) * 4096];
        s3 += p[(size_t)(k + 3) * 4096];
    }
    for (; k < nslice; ++k) s0 += p[(size_t)k * 4096];
    // i = ((mt*4+nt)*64 + lane)*4 + r  ->  u = mt*16 + 4*g + r, v = nt*16 + m
    const int r    = i & 3;
    const int lane = (i >> 2) & 63;
    const int fp   = i >> 8;
    const int u    = (fp >> 2) * 16 + (lane >> 4) * 4 + r;
    const int v    = (fp & 3) * 16 + (lane & 15);
    hist[lc * 4096 + u * 64 + v] = (s0 + s1) + (s2 + s3);
}

__global__ __launch_bounds__(256)
void finalize(const float* __restrict__ hist, float* __restrict__ out)
{
    const int l = blockIdx.x;
    const float* h = hist + l * 12288;
    float s = 0.f;
    for (int i = threadIdx.x; i < 12288; i += 256) s += h[i];
#pragma unroll
    for (int off = 32; off > 0; off >>= 1) s += __shfl_down(s, off);
    __shared__ float red[4];
    if ((threadIdx.x & 63) == 0) red[threadIdx.x >> 6] = s;
    __syncthreads();
    const float inv = 1.0f / (red[0] + red[1] + red[2] + red[3] + H_EPS);
    float* o = out + l * 12288;
    for (int i = threadIdx.x; i < 12288; i += 256) o[i] = h[i] * inv;
}

extern "C" void kernel_launch(void* const* d_in, const int* in_sizes, int n_in,
                              void* d_out, int out_size, void* d_ws, size_t ws_size,
                              hipStream_t stream)
{
    const float* x   = (const float*)d_in[0];
    float*       out = (float*)d_out;

    const size_t hist_bytes = (size_t)12 * 4096 * 4;   // 196608
    float* hist = (float*)d_ws;

    // npart: 64 preferred (768 blocks = 3/CU, all resident); halve to fit ws.
    // Partials (block-reduced): 12 * npart * 16 KB = 12.6 MB at npart=64.
    int npart = 64;
    while (npart > 1 &&
           hist_bytes + (size_t)12 * npart * 4096 * 4 > ws_size)
        npart >>= 1;

    float* partial = (float*)((char*)d_ws + hist_bytes);
    hist_kernel<<<dim3(npart, 12), 256, 0, stream>>>(x, partial, npart);
    reduce_partials<<<dim3(16, 12), 256, 0, stream>>>(partial, hist, npart);
    finalize<<<4, 256, 0, stream>>>(hist, out);
}

// Round 2
// 45.560 us; speedup vs baseline: 1.4978x; 1.2018x over previous
//
#include <hip/hip_runtime.h>
#include <hip/hip_bf16.h>

#define NPIX 65536
#define H_EPS 1e-6f
#define SIG2 4e-4f    // sigma^2; weights are 1/(d^2+sigma^2) — uniform
                      // sigma^-4 scale cancels in the final normalization

typedef __bf16 bf16x8 __attribute__((ext_vector_type(8)));
typedef float  f32x4  __attribute__((ext_vector_type(4)));

// hist[l,c,u,v] = sum_n du[l,n,c,u] * dv[l,n,c,v]
// Grid (npart, 12): block = 4 waves. Per 1024-pixel round: one vectorized
// staging pass + ONE barrier, then each wave independently computes 8 K=32
// chunks into its private 64x64 accumulator (4x4 fragments of
// mfma_f32_16x16x32_bf16). The chunk loop is deliberately NOT unrolled:
// unrolled, the body is ~3k instructions (~24 KB) and thrashes the I-cache
// (R4: all pipes idle at 51 us). Rolled body ~300 instr stays resident.
// Epilogue (R5): cross-wave LDS reduction (32 KB redv, 2 halves) so each
// BLOCK stores one 16 KB fragment-linear partial instead of 4 per-wave
// ones — partial traffic 50.3 -> 12.6 MB. LDS 44 KB keeps 3 blocks/CU.
// R6: the block also emits its total sum (one float, plain store) so the
// reducer can normalize directly — the finalize kernel and the 196 KB hist
// intermediate are gone (3 launches -> 2).
__global__ __launch_bounds__(256, 3)
void hist_kernel(const float* __restrict__ x, float* __restrict__ partial,
                 float* __restrict__ blocksum, int npart)
{
    const int part = blockIdx.x;
    const int lc   = blockIdx.y;      // 0..11
    const int l    = lc / 3;
    const int c    = lc % 3;
    const int tid  = threadIdx.x;
    const int wave = tid >> 6;
    const int lane = tid & 63;
    const int g    = lane >> 4;       // 16-lane group
    const int m    = lane & 15;       // row (A) / col (B) index

    __shared__ float stage[3][1024];  // Iu, Iv, Iy for 1024 pixels
                                      // (group read stride 8 dwords -> banks
                                      // {0,8,16,24}: conflict-free, measured)
    __shared__ f32x4 redv[4][8][64];  // 32 KB cross-wave reduction buffer
    __shared__ float bsum[4];

    float lin_t[4];
#pragma unroll
    for (int t = 0; t < 4; ++t)
        lin_t[t] = -3.0f + (float)(t * 16 + m) * (6.0f / 63.0f);

    f32x4 acc[4][4];
#pragma unroll
    for (int a = 0; a < 4; ++a)
#pragma unroll
        for (int b = 0; b < 4; ++b)
            acc[a][b] = (f32x4){0.f, 0.f, 0.f, 0.f};

    const float* xl = x + (size_t)l * 3u * NPIX;
    const int px_per_block = NPIX / npart;
    const int rounds = px_per_block >> 10;          // 1024-px rounds
    const int base = part * px_per_block;

    for (int rd = 0; rd < rounds; ++rd) {
        if (rd) __syncthreads();      // protect stage overwrite
        // ---- stage 1024 pixels: Iu_c, Iv_c, Iy (4 px/thread, vectorized) ----
        {
            const int p0 = base + (rd << 10) + (tid << 2);
            f32x4 r0 = *(const f32x4*)&xl[p0];
            f32x4 r1 = *(const f32x4*)&xl[p0 + NPIX];
            f32x4 r2 = *(const f32x4*)&xl[p0 + 2 * NPIX];
            f32x4 ou, ov, oy;
#pragma unroll
            for (int k = 0; k < 4; ++k) {
                float v0 = fminf(fmaxf(fmaf(r0[k], 0.5f, 0.5f), 0.f), 1.f);
                float v1 = fminf(fmaxf(fmaf(r1[k], 0.5f, 0.5f), 0.f), 1.f);
                float v2 = fminf(fmaxf(fmaf(r2[k], 0.5f, 0.5f), 0.f), 1.f);
                oy[k] = sqrtf(fmaf(v0, v0, fmaf(v1, v1, fmaf(v2, v2, H_EPS))));
                float l0 = __logf(v0 + H_EPS);
                float l1 = __logf(v1 + H_EPS);
                float l2 = __logf(v2 + H_EPS);
                // Iu = logI - logI[..., [1,0,0]] ; Iv = logI - logI[..., [2,2,1]]
                float lcur = (c == 0) ? l0 : ((c == 1) ? l1 : l2);
                float lu   = (c == 0) ? l1 : l0;
                float lv   = (c == 2) ? l1 : l2;
                ou[k] = lcur - lu;
                ov[k] = lcur - lv;
            }
            *(f32x4*)&stage[0][tid << 2] = ou;
            *(f32x4*)&stage[1][tid << 2] = ov;
            *(f32x4*)&stage[2][tid << 2] = oy;
        }
        __syncthreads();

        // ---- each wave: 8 independent K=32 chunks, no further sync ----
        // NOT unrolled (I-cache); all inner indexing stays compile-time.
#pragma unroll 1
        for (int chunk = 0; chunk < 8; ++chunk) {
            const int pb = wave * 256 + chunk * 32 + g * 8;
            float iu[8], iv[8], iy[8];
#pragma unroll
            for (int j = 0; j < 8; ++j) {       // 16-lane broadcast reads
                iu[j] = stage[0][pb + j];
                iv[j] = stage[1][pb + j];
                iy[j] = stage[2][pb + j];
            }
            bf16x8 afrag[4], bfrag[4];
#pragma unroll
            for (int j = 0; j < 8; ++j) {
#pragma unroll
                for (int t = 0; t < 4; ++t) {
                    float da = iu[j] - lin_t[t];
                    afrag[t][j] = (__bf16)(iy[j] *
                        __builtin_amdgcn_rcpf(fmaf(da, da, SIG2)));
                    float db = iv[j] - lin_t[t];
                    bfrag[t][j] = (__bf16)
                        __builtin_amdgcn_rcpf(fmaf(db, db, SIG2));
                }
            }
#pragma unroll
            for (int mt = 0; mt < 4; ++mt)
#pragma unroll
                for (int nt = 0; nt < 4; ++nt)
                    acc[mt][nt] = __builtin_amdgcn_mfma_f32_16x16x32_bf16(
                        afrag[mt], bfrag[nt], acc[mt][nt], 0, 0, 0);
        }
    }

    // ---- cross-wave LDS reduction: ONE 16 KB partial per block ----
    // Two halves of 8 fragments each; fragment-linear order preserved so
    // the reducer's unscramble is unchanged (frag index = h*8 + f).
    float tsum = 0.f;                 // block total for normalization
    f32x4* dstv = (f32x4*)(partial + (size_t)(lc * npart + part) * 4096);
#pragma unroll
    for (int h = 0; h < 2; ++h) {
        if (h) __syncthreads();       // half-0 reads done before overwrite
#pragma unroll
        for (int f = 0; f < 8; ++f) {
            const int frag = h * 8 + f;
            redv[wave][f][lane] = acc[frag >> 2][frag & 3];
        }
        __syncthreads();
#pragma unroll
        for (int q = 0; q < 2; ++q) {
            const int idx = q * 256 + tid;   // frag-linear within this half
            f32x4 s = redv[0][idx >> 6][idx & 63];
            s += redv[1][idx >> 6][idx & 63];
            s += redv[2][idx >> 6][idx & 63];
            s += redv[3][idx >> 6][idx & 63];
            dstv[h * 512 + idx] = s;         // fully coalesced dwordx4
            tsum += (s[0] + s[1]) + (s[2] + s[3]);
        }
    }

    // ---- block-total store (plain store: no atomics, no init needed) ----
#pragma unroll
    for (int off = 32; off > 0; off >>= 1)
        tsum += __shfl_down(tsum, off);
    if (lane == 0) bsum[wave] = tsum;
    __syncthreads();
    if (tid == 0)
        blocksum[lc * npart + part] = (bsum[0] + bsum[1]) + (bsum[2] + bsum[3]);
}

// out[lc][u][v] = (sum_s partial[lc][s][frag(u,v)]) / (sum hists + eps);
// reads fully coalesced in fragment order, the (u,v) unscramble happens on
// the tiny write side. Norm denominator: uniform sum of this image's
// 3*npart block sums (768 B, L2-hit) — normalization fused, no 3rd kernel.
__global__ __launch_bounds__(256)
void reduce_partials(const float* __restrict__ partial,
                     const float* __restrict__ blocksum,
                     float* __restrict__ out, int npart)
{
    const int lc = blockIdx.y;
    const int l  = lc / 3;
    const int i  = (blockIdx.x << 8) | threadIdx.x;   // fragment-linear index
    const float* p = partial + (size_t)lc * npart * 4096 + i;
    float s0 = 0.f, s1 = 0.f, s2 = 0.f, s3 = 0.f;
    int k = 0;
    for (; k + 4 <= npart; k += 4) {
        s0 += p[(size_t)(k + 0) * 4096];
        s1 += p[(size_t)(k + 1) * 4096];
        s2 += p[(size_t)(k + 2) * 4096];
        s3 += p[(size_t)(k + 3) * 4096];
    }
    for (; k < npart; ++k) s0 += p[(size_t)k * 4096];

    // uniform norm (all threads compute the same value -> scalar loads)
    float norm = H_EPS;
    const float* bs = blocksum + (size_t)l * 3 * npart;
    for (int j = 0; j < 3 * npart; ++j) norm += bs[j];
    const float inv = 1.0f / norm;

    // i = ((mt*4+nt)*64 + lane)*4 + r  ->  u = mt*16 + 4*g + r, v = nt*16 + m
    const int r    = i & 3;
    const int lane = (i >> 2) & 63;
    const int fp   = i >> 8;
    const int u    = (fp >> 2) * 16 + (lane >> 4) * 4 + r;
    const int v    = (fp & 3) * 16 + (lane & 15);
    out[lc * 4096 + u * 64 + v] = ((s0 + s1) + (s2 + s3)) * inv;
}

extern "C" void kernel_launch(void* const* d_in, const int* in_sizes, int n_in,
                              void* d_out, int out_size, void* d_ws, size_t ws_size,
                              hipStream_t stream)
{
    const float* x   = (const float*)d_in[0];
    float*       out = (float*)d_out;

    // ws layout: blocksum (16 KB slot, 12*npart floats used) | partials
    const size_t bsum_bytes = 16384;
    float* blocksum = (float*)d_ws;

    // npart: 64 preferred (768 blocks = 3/CU, all resident); halve to fit ws.
    // Partials (block-reduced): 12 * npart * 16 KB = 12.6 MB at npart=64.
    int npart = 64;
    while (npart > 1 &&
           bsum_bytes + (size_t)12 * npart * 4096 * 4 > ws_size)
        npart >>= 1;

    float* partial = (float*)((char*)d_ws + bsum_bytes);
    hist_kernel<<<dim3(npart, 12), 256, 0, stream>>>(x, partial, blocksum, npart);
    reduce_partials<<<dim3(16, 12), 256, 0, stream>>>(partial, blocksum, out, npart);
}